// Round 1
// baseline (1211.414 us; speedup 1.0000x reference)
//
#include <hip/hip_runtime.h>
#include <cstdint>
#include <cstddef>

typedef __bf16 bf16_t;
typedef __bf16 bf16x8 __attribute__((ext_vector_type(8)));
typedef __bf16 bf16x4 __attribute__((ext_vector_type(4)));
typedef float floatx4 __attribute__((ext_vector_type(4)));

#define B_  2
#define T_  2048
#define C_  2048
#define H_  16
#define HD_ 128

// ---------------- convert fp32 -> bf16 (flat) ----------------
__global__ __launch_bounds__(256) void cvt_f32_bf16(const float* __restrict__ in,
                                                    bf16_t* __restrict__ out, int n4) {
  int i = blockIdx.x * 256 + threadIdx.x;
  if (i >= n4) return;
  const float4 v = ((const float4*)in)[i];
  bf16x4 o;
  o[0] = (bf16_t)v.x; o[1] = (bf16_t)v.y; o[2] = (bf16_t)v.z; o[3] = (bf16_t)v.w;
  ((bf16x4*)out)[i] = o;
}

// ------- transpose + convert: W[Kd][Nd] fp32 -> Wt[Nd][Kd] bf16 -------
__global__ __launch_bounds__(256) void transpose_cvt(const float* __restrict__ W,
                                                     bf16_t* __restrict__ Wt,
                                                     int Kd, int Nd) {
  __shared__ float tile[32][33];
  const int tx = threadIdx.x, ty = threadIdx.y;
  const int n0 = blockIdx.x * 32, k0 = blockIdx.y * 32;
#pragma unroll
  for (int j = ty; j < 32; j += 8)
    tile[j][tx] = W[(size_t)(k0 + j) * Nd + n0 + tx];
  __syncthreads();
#pragma unroll
  for (int j = ty; j < 32; j += 8)
    Wt[(size_t)(n0 + j) * Kd + k0 + tx] = (bf16_t)tile[tx][j];
}

// ---------------- GEMM: C[M][N] = A[M][K] * Bt[N][K]^T + bias ----------------
// MODE 0: scatter epilogue -> Q[B,H,T,hd], K[B,H,T,hd], V^T[B,H,hd,T] (bf16)
// MODE 1: fp32 C output
#define TM 128
#define TN 128
#define BK 64
#define LDK (BK + 8)

template <int MODE>
__global__ __launch_bounds__(256) void gemm_bt(
    const bf16_t* __restrict__ A, const bf16_t* __restrict__ Bt,
    const float* __restrict__ bias, float* __restrict__ Cout,
    bf16_t* __restrict__ Qo, bf16_t* __restrict__ Ko, bf16_t* __restrict__ Vo,
    int M, int N, int K) {
  __shared__ bf16_t As[TM][LDK];
  __shared__ bf16_t Bs[TN][LDK];
  const int tid = threadIdx.x;
  const int wave = tid >> 6, lane = tid & 63;
  const int quad = lane >> 4, l15 = lane & 15;
  const int bm = blockIdx.y * TM, bn = blockIdx.x * TN;
  const int wm = (wave >> 1) * 64, wn = (wave & 1) * 64;

  floatx4 acc[4][4] = {};

  for (int k0 = 0; k0 < K; k0 += BK) {
    uint4 ar[4], br[4];
#pragma unroll
    for (int i = 0; i < 4; ++i) {
      int c = i * 256 + tid;
      int r = c >> 3, col = (c & 7) * 8;
      ar[i] = *(const uint4*)(A + (size_t)(bm + r) * K + k0 + col);
      br[i] = *(const uint4*)(Bt + (size_t)(bn + r) * K + k0 + col);
    }
    __syncthreads();
#pragma unroll
    for (int i = 0; i < 4; ++i) {
      int c = i * 256 + tid;
      int r = c >> 3, col = (c & 7) * 8;
      *(uint4*)&As[r][col] = ar[i];
      *(uint4*)&Bs[r][col] = br[i];
    }
    __syncthreads();
#pragma unroll
    for (int kc = 0; kc < 2; ++kc) {
      bf16x8 af[4], bf[4];
#pragma unroll
      for (int i = 0; i < 4; ++i)
        af[i] = *(const bf16x8*)&As[wm + i * 16 + l15][kc * 32 + quad * 8];
#pragma unroll
      for (int j = 0; j < 4; ++j)
        bf[j] = *(const bf16x8*)&Bs[wn + j * 16 + l15][kc * 32 + quad * 8];
#pragma unroll
      for (int i = 0; i < 4; ++i)
#pragma unroll
        for (int j = 0; j < 4; ++j)
          acc[i][j] = __builtin_amdgcn_mfma_f32_16x16x32_bf16(af[i], bf[j], acc[i][j], 0, 0, 0);
    }
  }

#pragma unroll
  for (int i = 0; i < 4; ++i) {
#pragma unroll
    for (int j = 0; j < 4; ++j) {
#pragma unroll
      for (int r = 0; r < 4; ++r) {
        int m = bm + wm + i * 16 + quad * 4 + r;
        int n = bn + wn + j * 16 + l15;
        float val = acc[i][j][r] + bias[n];
        if (MODE == 1) {
          Cout[(size_t)m * N + n] = val;
        } else {
          int which = n >> 11;
          int cc = n & 2047;
          int h = cc >> 7, d = cc & 127;
          int b = m >> 11, t = m & 2047;
          bf16_t bv = (bf16_t)val;
          if (which == 0)
            Qo[(((size_t)(b * H_ + h)) * T_ + t) * HD_ + d] = bv;
          else if (which == 1)
            Ko[(((size_t)(b * H_ + h)) * T_ + t) * HD_ + d] = bv;
          else
            Vo[(((size_t)(b * H_ + h)) * HD_ + d) * T_ + t] = bv;
        }
      }
    }
  }
}

// ---------------- causal flash attention ----------------
// Q,K: [B,H,T,hd] bf16 ; Vt: [B,H,hd,T] bf16 ; O: [B,T,H*hd] bf16
// one wave = 16 q rows; block = 4 waves = 64 q rows; no inter-wave sync.
__global__ __launch_bounds__(256) void attn(const bf16_t* __restrict__ Q,
                                            const bf16_t* __restrict__ Kg,
                                            const bf16_t* __restrict__ Vt,
                                            bf16_t* __restrict__ O) {
  __shared__ bf16_t Plds[4][16][40];
  const int wave = threadIdx.x >> 6, lane = threadIdx.x & 63;
  const int quad = lane >> 4, l15 = lane & 15;
  const int bh = blockIdx.y;
  const int b = bh >> 4, h = bh & 15;
  const int q0 = blockIdx.x * 64 + wave * 16;

  const bf16_t* Qh = Q + (size_t)bh * T_ * HD_;
  const bf16_t* Kh = Kg + (size_t)bh * T_ * HD_;
  const bf16_t* Vh = Vt + (size_t)bh * HD_ * T_;

  bf16x8 qf[4];
#pragma unroll
  for (int kk = 0; kk < 4; ++kk)
    qf[kk] = *(const bf16x8*)(Qh + (size_t)(q0 + l15) * HD_ + kk * 32 + quad * 8);

  floatx4 oacc[8] = {};
  float m_i[4], l_i[4];
#pragma unroll
  for (int r = 0; r < 4; ++r) { m_i[r] = -3.0e38f; l_i[r] = 0.0f; }

  const float scale = 0.08838834764831843f;  // 1/sqrt(128)
  const int nch = (q0 + 15) / 32 + 1;

  for (int ch = 0; ch < nch; ++ch) {
    const int kt0 = ch * 32;
    floatx4 s0 = {}, s1 = {};
#pragma unroll
    for (int kk = 0; kk < 4; ++kk) {
      bf16x8 kf0 = *(const bf16x8*)(Kh + (size_t)(kt0 + l15) * HD_ + kk * 32 + quad * 8);
      s0 = __builtin_amdgcn_mfma_f32_16x16x32_bf16(qf[kk], kf0, s0, 0, 0, 0);
      bf16x8 kf1 = *(const bf16x8*)(Kh + (size_t)(kt0 + 16 + l15) * HD_ + kk * 32 + quad * 8);
      s1 = __builtin_amdgcn_mfma_f32_16x16x32_bf16(qf[kk], kf1, s1, 0, 0, 0);
    }
    float sv0[4], sv1[4], mx[4];
#pragma unroll
    for (int r = 0; r < 4; ++r) {
      int qq = q0 + quad * 4 + r;
      sv0[r] = ((kt0 + l15) <= qq) ? s0[r] * scale : -3.0e38f;
      sv1[r] = ((kt0 + 16 + l15) <= qq) ? s1[r] * scale : -3.0e38f;
      mx[r] = fmaxf(sv0[r], sv1[r]);
    }
#pragma unroll
    for (int off = 8; off >= 1; off >>= 1)
#pragma unroll
      for (int r = 0; r < 4; ++r) mx[r] = fmaxf(mx[r], __shfl_xor(mx[r], off));

    float alpha[4], ps[4];
#pragma unroll
    for (int r = 0; r < 4; ++r) {
      float mn = fmaxf(m_i[r], mx[r]);
      alpha[r] = __expf(m_i[r] - mn);
      m_i[r] = mn;
      float p0 = __expf(sv0[r] - mn);
      float p1 = __expf(sv1[r] - mn);
      ps[r] = p0 + p1;
      Plds[wave][quad * 4 + r][l15] = (bf16_t)p0;
      Plds[wave][quad * 4 + r][16 + l15] = (bf16_t)p1;
    }
#pragma unroll
    for (int off = 8; off >= 1; off >>= 1)
#pragma unroll
      for (int r = 0; r < 4; ++r) ps[r] += __shfl_xor(ps[r], off);
#pragma unroll
    for (int r = 0; r < 4; ++r) l_i[r] = l_i[r] * alpha[r] + ps[r];
#pragma unroll
    for (int dt = 0; dt < 8; ++dt)
#pragma unroll
      for (int r = 0; r < 4; ++r) oacc[dt][r] *= alpha[r];

    // P (C/D layout) -> A layout via per-wave LDS round trip
    bf16x8 pf = *(const bf16x8*)&Plds[wave][l15][quad * 8];
#pragma unroll
    for (int dt = 0; dt < 8; ++dt) {
      bf16x8 vf = *(const bf16x8*)(Vh + (size_t)(dt * 16 + l15) * T_ + kt0 + quad * 8);
      oacc[dt] = __builtin_amdgcn_mfma_f32_16x16x32_bf16(pf, vf, oacc[dt], 0, 0, 0);
    }
  }

#pragma unroll
  for (int dt = 0; dt < 8; ++dt) {
#pragma unroll
    for (int r = 0; r < 4; ++r) {
      int qq = q0 + quad * 4 + r;
      int d = dt * 16 + l15;
      float v = oacc[dt][r] / l_i[r];
      O[((size_t)(b * T_ + qq)) * C_ + h * HD_ + d] = (bf16_t)v;
    }
  }
}

// ---------------- launch ----------------
extern "C" void kernel_launch(void* const* d_in, const int* in_sizes, int n_in,
                              void* d_out, int out_size, void* d_ws, size_t ws_size,
                              hipStream_t stream) {
  const float* x      = (const float*)d_in[0];
  const float* w_attn = (const float*)d_in[1];
  const float* b_attn = (const float*)d_in[2];
  const float* w_proj = (const float*)d_in[3];
  const float* b_proj = (const float*)d_in[4];
  float* out = (float*)d_out;

  char* p = (char*)d_ws;
  bf16_t* xb  = (bf16_t*)p; p += (size_t)4096 * 2048 * 2;   // x bf16 [B*T][C]
  bf16_t* waT = (bf16_t*)p; p += (size_t)6144 * 2048 * 2;   // w_attn^T bf16 [3C][C]
  bf16_t* wpT = (bf16_t*)p; p += (size_t)2048 * 2048 * 2;   // w_proj^T bf16 [C][C]
  bf16_t* Qb  = (bf16_t*)p; p += (size_t)32 * 2048 * 128 * 2;  // [B,H,T,hd]
  bf16_t* Kb  = (bf16_t*)p; p += (size_t)32 * 2048 * 128 * 2;  // [B,H,T,hd]
  bf16_t* Vb  = (bf16_t*)p; p += (size_t)32 * 2048 * 128 * 2;  // [B,H,hd,T]
  bf16_t* Ob  = (bf16_t*)p; p += (size_t)4096 * 2048 * 2;      // [B*T][C]

  cvt_f32_bf16<<<8192, 256, 0, stream>>>(x, xb, 2097152);
  transpose_cvt<<<dim3(6144 / 32, 2048 / 32), dim3(32, 8), 0, stream>>>(w_attn, waT, 2048, 6144);
  transpose_cvt<<<dim3(2048 / 32, 2048 / 32), dim3(32, 8), 0, stream>>>(w_proj, wpT, 2048, 2048);

  gemm_bt<0><<<dim3(6144 / TN, 4096 / TM), 256, 0, stream>>>(
      xb, waT, b_attn, nullptr, Qb, Kb, Vb, 4096, 6144, 2048);

  attn<<<dim3(2048 / 64, 32), 256, 0, stream>>>(Qb, Kb, Vb, Ob);

  gemm_bt<1><<<dim3(2048 / TN, 4096 / TM), 256, 0, stream>>>(
      Ob, wpT, b_proj, out, nullptr, nullptr, nullptr, 4096, 2048, 2048);
}